// Round 6
// baseline (906.335 us; speedup 1.0000x reference)
//
#include <hip/hip_runtime.h>

#define NN 50000
#define NE 600000
#define NBG 782  // divup(NN,64)

typedef __attribute__((ext_vector_type(8))) short short8;
typedef __attribute__((ext_vector_type(4))) float f32x4;

static inline int divup(int a, int b) { return (a + b - 1) / b; }

__device__ inline unsigned short f2bf(float f) {
    unsigned int u = __float_as_uint(f);
    unsigned int r = (u + 0x7FFFu + ((u >> 16) & 1u)) >> 16;
    return (unsigned short)r;
}
__device__ inline float bflo(unsigned int u) { return __uint_as_float(u << 16); }
__device__ inline float bfhi(unsigned int u) { return __uint_as_float(u & 0xFFFF0000u); }

// ---------------- fused prep: zero counters + X->bf16 cast + weight prep ----------------
#define PREP_Z (4 * NN)
#define PREP_X (NN * 32)
#define PREP_W (6 * 16384)
__global__ void k_prep(const float* __restrict__ X,
                       const float* __restrict__ encW1, const float* __restrict__ encW2,
                       const float* __restrict__ g1W, const float* __restrict__ g2W,
                       const float* __restrict__ g3W,
                       int* __restrict__ cnts, unsigned short* __restrict__ Xb,
                       unsigned short* __restrict__ WtS) {
    int i = blockIdx.x * blockDim.x + threadIdx.x;
    const int stride = gridDim.x * blockDim.x;
    const int T = PREP_Z + PREP_X + PREP_W;
    for (; i < T; i += stride) {
        if (i < PREP_Z) {
            cnts[i] = 0;
        } else if (i < PREP_Z + PREP_X) {
            int j = i - PREP_Z;
            float4 v = ((const float4*)X)[j];
            ushort4 o;
            o.x = f2bf(v.x); o.y = f2bf(v.y); o.z = f2bf(v.z); o.w = f2bf(v.w);
            ((ushort4*)Xb)[j] = o;
        } else {
            // W^T bf16, XOR-swizzled: elem (n,k) at byte ((n<<8)|(k<<1)) ^ ((n&7)<<4)
            int j = i - (PREP_Z + PREP_X);
            int m = j >> 14;
            int r = j & 16383;
            int k = r >> 7;
            int n = r & 127;
            const float* src;
            switch (m) {
                case 0: src = encW1; break;
                case 1: src = encW2; break;
                case 2: src = g1W; break;
                case 3: src = g1W + 16384; break;
                case 4: src = g2W; break;
                default: src = g3W; break;
            }
            unsigned short v = f2bf(src[k * 128 + n]);
            unsigned int byte = (((unsigned)n << 8) | ((unsigned)k << 1)) ^ (((unsigned)n & 7u) << 4);
            WtS[(m << 14) + (byte >> 1)] = v;
        }
    }
}

// scalars: sqrt_ab, sqrt_1m, cvec[128] = temb @ g1_W[256:384,:], zero L out
__global__ void k_scalars(const int* __restrict__ t_p,
                          const float* __restrict__ tmW1, const float* __restrict__ tmb1,
                          const float* __restrict__ tmW2, const float* __restrict__ tmb2,
                          const float* __restrict__ g1W,
                          float* __restrict__ scal, float* __restrict__ lout) {
    __shared__ float e32[32];
    __shared__ float temb[128];
    const int tid = threadIdx.x;
    const int t = t_p[0];
    if (tid < 32) {
        float x = (float)t * tmW1[tid] + tmb1[tid];
        e32[tid] = x / (1.0f + expf(-x));  // silu
    }
    __syncthreads();
    float acc = tmb2[tid];
    for (int j = 0; j < 32; ++j) acc += e32[j] * tmW2[j * 128 + tid];
    temb[tid] = acc;
    __syncthreads();
    float cv = 0.0f;
    for (int j = 0; j < 128; ++j) cv += temb[j] * g1W[(256 + j) * 128 + tid];
    scal[2 + tid] = cv;
    if (tid == 0) {
        double ab = 1.0;
        for (int i = 0; i <= t; ++i) {
            double beta = 1e-4 + (0.02 - 1e-4) * (double)i / 99.0;
            ab *= (1.0 - beta);
        }
        scal[0] = (float)sqrt(ab);
        scal[1] = (float)sqrt(1.0 - ab);
        lout[0] = 0.0f;
    }
}

// both graphs' degree histograms in one dispatch
__global__ void k_hist2(const int* __restrict__ dst1, const int* __restrict__ dst2,
                        int* __restrict__ cnt1, int* __restrict__ cnt2) {
    int i = blockIdx.x * blockDim.x + threadIdx.x;
    if (i < NE) atomicAdd(&cnt1[dst1[i]], 1);
    else if (i < 2 * NE) atomicAdd(&cnt2[dst2[i - NE]], 1);
}

// single-block full exclusive scan over [cnt1;cnt2] (2N) -> rowptr1/rowptr2 + dinv
__global__ __launch_bounds__(1024) void k_scanfull(
    const int* __restrict__ cnt, int* __restrict__ rowptr1, int* __restrict__ rowptr2,
    float* __restrict__ dinv1, float* __restrict__ dinv2) {
    __shared__ int part[1024];
    const int tid = threadIdx.x;
    const int total = 2 * NN;
    const int per = (total + 1023) >> 10;  // 98
    int s0 = tid * per; if (s0 > total) s0 = total;
    int s1 = s0 + per; if (s1 > total) s1 = total;
    int sum = 0;
    for (int i = s0; i < s1; ++i) sum += cnt[i];
    part[tid] = sum;
    __syncthreads();
    for (int off = 1; off < 1024; off <<= 1) {
        int v = (tid >= off) ? part[tid - off] : 0;
        __syncthreads();
        part[tid] += v;
        __syncthreads();
    }
    int run = part[tid] - sum;  // exclusive prefix of this thread's chunk
    for (int i = s0; i < s1; ++i) {
        int c = cnt[i];
        if (i < NN) {
            rowptr1[i] = run;
            dinv1[i] = rsqrtf((float)c + 1.0f);
        } else {
            rowptr2[i - NN] = run - NE;
            dinv2[i - NN] = rsqrtf((float)c + 1.0f);
        }
        run += c;
    }
    if (tid == 0) { rowptr1[NN] = NE; rowptr2[NN] = NE; }
}

// both graphs' CSR fill in one dispatch
__global__ void k_fill2(const int* __restrict__ src1, const int* __restrict__ dst1,
                        const int* __restrict__ src2, const int* __restrict__ dst2,
                        const int* __restrict__ rowptr1, const int* __restrict__ rowptr2,
                        int* __restrict__ fill1, int* __restrict__ fill2,
                        int* __restrict__ col1, int* __restrict__ col2) {
    int i = blockIdx.x * blockDim.x + threadIdx.x;
    if (i < NE) {
        int d = dst1[i];
        int p = atomicAdd(&fill1[d], 1);
        col1[rowptr1[d] + p] = src1[i];
    } else if (i < 2 * NE) {
        int j = i - NE;
        int d = dst2[j];
        int p = atomicAdd(&fill2[d], 1);
        col2[rowptr2[d] + p] = src2[j];
    }
}

// ---------------- combined MFMA GEMM (two units) ----------------
// unit u: out_u = A_u@Wa (+ B_u@Wb) (+ cvec).  Wa/Wb: swizzled 32KB W^T images.
// Block: 64 rows, 4 waves; wave = 16 rows x 128 cols; 16x16x32 MFMA.
__global__ __launch_bounds__(256) void k_mgemm2(
    const unsigned short* __restrict__ A0, const unsigned short* __restrict__ B0,
    unsigned short* __restrict__ out0,
    const unsigned short* __restrict__ A1, const unsigned short* __restrict__ B1,
    unsigned short* __restrict__ out1,
    const unsigned short* __restrict__ Wa, const unsigned short* __restrict__ Wb,
    const float* __restrict__ cvec) {
    __shared__ unsigned short sW[16384];  // 32KB swizzled W^T
    const int unit = blockIdx.x / NBG;
    const int blk = blockIdx.x - unit * NBG;
    const unsigned short* A = unit ? A1 : A0;
    const unsigned short* B = unit ? B1 : B0;
    unsigned short* out = unit ? out1 : out0;

    const int tid = threadIdx.x;
    const int wv = tid >> 6;
    const int l = tid & 63;
    const int lrow = l & 15;   // A-row / C-col within tile
    const int lk = l >> 4;     // 0..3: K-subgroup / C-row-group
    const int r0 = blk * 64 + wv * 16;

    f32x4 acc[8];
#pragma unroll
    for (int ct = 0; ct < 8; ++ct) acc[ct] = (f32x4){0.f, 0.f, 0.f, 0.f};

    const unsigned short* Aptr[2] = {A, B};
    const unsigned short* Wptr[2] = {Wa, Wb};
    const int np = (B != nullptr) ? 2 : 1;

    int arow = r0 + lrow;
    if (arow >= NN) arow = NN - 1;

    for (int p = 0; p < np; ++p) {
        __syncthreads();  // protect sW from previous pass readers
        {
            const uint4* s = (const uint4*)Wptr[p];
            uint4* d = (uint4*)sW;
#pragma unroll
            for (int j = 0; j < 8; ++j) d[tid + j * 256] = s[tid + j * 256];
        }
        __syncthreads();
        const unsigned short* abase = Aptr[p] + (size_t)arow * 128 + lk * 8;
#pragma unroll
        for (int ks = 0; ks < 4; ++ks) {
            short8 af = *(const short8*)(abase + ks * 32);
            const int kb2 = (lk * 8 + ks * 32) << 1;  // byte offset of k-base
#pragma unroll
            for (int ct = 0; ct < 8; ++ct) {
                int n = ct * 16 + lrow;
                int byteoff = ((n << 8) + kb2) ^ ((l & 7) << 4);
                short8 bf = *(const short8*)((const char*)sW + byteoff);
                acc[ct] = __builtin_amdgcn_mfma_f32_16x16x32_bf16(af, bf, acc[ct], 0, 0, 0);
            }
        }
    }
    // epilogue: C[row = r0 + lk*4 + reg][col = ct*16 + lrow]
#pragma unroll
    for (int ct = 0; ct < 8; ++ct) {
        float cv = cvec ? cvec[ct * 16 + lrow] : 0.0f;
#pragma unroll
        for (int rg = 0; rg < 4; ++rg) {
            int row = r0 + lk * 4 + rg;
            if (row < NN) out[(size_t)row * 128 + ct * 16 + lrow] = f2bf(acc[ct][rg] + cv);
        }
    }
}

// ---------------- combined GCN aggregation (two units, bf16 in/out) ----------------
// wave w<NN: graph1 on in0->out0; else graph2 on in1->out1.
// Quarter-wave (16 lanes x 16B) per gathered row, 2-deep pipelined gather.
__global__ __launch_bounds__(256) void k_agg2(
    const unsigned short* __restrict__ in0, const unsigned short* __restrict__ in1,
    const int* __restrict__ rowptr1, const int* __restrict__ col1, const float* __restrict__ dinv1,
    const int* __restrict__ rowptr2, const int* __restrict__ col2, const float* __restrict__ dinv2,
    const float* __restrict__ bias,
    unsigned short* __restrict__ out0, unsigned short* __restrict__ out1, int do_relu) {
    const int gw = (blockIdx.x * blockDim.x + threadIdx.x) >> 6;
    if (gw >= 2 * NN) return;
    const int unit = gw >= NN;
    const int d = unit ? gw - NN : gw;
    const unsigned short* h = unit ? in1 : in0;
    const int* rowptr = unit ? rowptr2 : rowptr1;
    const int* colA = unit ? col2 : col1;
    const float* dinv = unit ? dinv2 : dinv1;
    unsigned short* out = unit ? out1 : out0;

    const int l = threadIdx.x & 63;
    const int lg = l >> 4;   // quarter-wave group 0..3
    const int ll = l & 15;   // owns features ll*8..ll*8+7
    const float di = dinv[d];

    float acc[8];
#pragma unroll
    for (int k = 0; k < 8; ++k) acc[k] = 0.0f;

    const int e0 = rowptr[d];
    const int e1 = rowptr[d + 1];
    for (int base = e0; base < e1; base += 64) {
        int cnt = min(64, e1 - base);
        int cs = 0;
        float ws = 0.0f;
        if (base + l < e1) {
            cs = colA[base + l];
            ws = dinv[cs];
        }
        // 2-deep pipelined gather: prefetch next 4-edge group before consuming current
        int s0 = __shfl(cs, lg);
        float w0 = __shfl(ws, lg);
        uint4 u0 = *((const uint4*)(h + (size_t)s0 * 128) + ll);
        for (int j4 = 4; j4 < cnt; j4 += 4) {
            int s1 = __shfl(cs, j4 + lg);
            float w1 = __shfl(ws, j4 + lg);
            uint4 u1 = *((const uint4*)(h + (size_t)s1 * 128) + ll);
            acc[0] += w0 * bflo(u0.x);
            acc[1] += w0 * bfhi(u0.x);
            acc[2] += w0 * bflo(u0.y);
            acc[3] += w0 * bfhi(u0.y);
            acc[4] += w0 * bflo(u0.z);
            acc[5] += w0 * bfhi(u0.z);
            acc[6] += w0 * bflo(u0.w);
            acc[7] += w0 * bfhi(u0.w);
            u0 = u1;
            w0 = w1;
        }
        acc[0] += w0 * bflo(u0.x);
        acc[1] += w0 * bfhi(u0.x);
        acc[2] += w0 * bflo(u0.y);
        acc[3] += w0 * bfhi(u0.y);
        acc[4] += w0 * bflo(u0.z);
        acc[5] += w0 * bfhi(u0.z);
        acc[6] += w0 * bflo(u0.w);
        acc[7] += w0 * bfhi(u0.w);
    }
    // combine the 4 groups
#pragma unroll
    for (int k = 0; k < 8; ++k) {
        acc[k] += __shfl_xor(acc[k], 16);
        acc[k] += __shfl_xor(acc[k], 32);
    }
    if (lg == 0) {
        uint4 su = *((const uint4*)(h + (size_t)d * 128) + ll);
        float4 b0 = ((const float4*)bias)[ll * 2];
        float4 b1 = ((const float4*)bias)[ll * 2 + 1];
        float sf[8] = {bflo(su.x), bfhi(su.x), bflo(su.y), bfhi(su.y),
                       bflo(su.z), bfhi(su.z), bflo(su.w), bfhi(su.w)};
        float bb[8] = {b0.x, b0.y, b0.z, b0.w, b1.x, b1.y, b1.z, b1.w};
        unsigned short o[8];
#pragma unroll
        for (int k = 0; k < 8; ++k) {
            float v = di * (acc[k] + di * sf[k]) + bb[k];
            if (do_relu) v = fmaxf(v, 0.0f);
            o[k] = f2bf(v);
        }
        uint4 ov;
        ov.x = (unsigned int)o[0] | ((unsigned int)o[1] << 16);
        ov.y = (unsigned int)o[2] | ((unsigned int)o[3] << 16);
        ov.z = (unsigned int)o[4] | ((unsigned int)o[5] << 16);
        ov.w = (unsigned int)o[6] | ((unsigned int)o[7] << 16);
        *((uint4*)(out + (size_t)d * 128) + ll) = ov;
    }
}

// ---------------- h_diff (f32 out) + h_t (bf16) ----------------
__global__ void k_mix(const unsigned short* __restrict__ F1, const unsigned short* __restrict__ F2,
                      const float* __restrict__ n1, const float* __restrict__ n2,
                      const float* __restrict__ scal, float* __restrict__ hdiff,
                      unsigned short* __restrict__ B1, unsigned short* __restrict__ B2, int total2) {
    const float sa = scal[0];
    const float sm = scal[1];
    int i = blockIdx.x * blockDim.x + threadIdx.x;
    const int stride = gridDim.x * blockDim.x;
    for (; i < total2; i += stride) {
        unsigned int u1 = ((const unsigned int*)F1)[i];
        unsigned int u2 = ((const unsigned int*)F2)[i];
        float a0 = bflo(u1), a1 = bfhi(u1);
        float b0 = bflo(u2), b1 = bfhi(u2);
        float2 x = ((const float2*)n1)[i];
        float2 y = ((const float2*)n2)[i];
        float2 hd;
        hd.x = 0.5f * (a0 + b0);
        hd.y = 0.5f * (a1 + b1);
        ((float2*)hdiff)[i] = hd;
        float h1x = sa * a0 + sm * x.x, h1y = sa * a1 + sm * x.y;
        float h2x = sa * b0 + sm * y.x, h2y = sa * b1 + sm * y.y;
        ((unsigned int*)B1)[i] = (unsigned int)f2bf(h1x) | ((unsigned int)f2bf(h1y) << 16);
        ((unsigned int*)B2)[i] = (unsigned int)f2bf(h2x) | ((unsigned int)f2bf(h2y) << 16);
    }
}

// ---------------- L_diff ----------------
__global__ void k_loss(const unsigned short* __restrict__ P1, const unsigned short* __restrict__ P2,
                       const float* __restrict__ n1, const float* __restrict__ n2,
                       float* __restrict__ outs, int total2, float inv_total) {
    float s = 0.0f;
    int i = blockIdx.x * blockDim.x + threadIdx.x;
    const int stride = gridDim.x * blockDim.x;
    for (; i < total2; i += stride) {
        unsigned int u1 = ((const unsigned int*)P1)[i];
        unsigned int u2 = ((const unsigned int*)P2)[i];
        float2 x = ((const float2*)n1)[i];
        float2 y = ((const float2*)n2)[i];
        float d0 = bflo(u1) - x.x, d1 = bfhi(u1) - x.y;
        float d2 = bflo(u2) - y.x, d3 = bfhi(u2) - y.y;
        s += d0 * d0 + d1 * d1 + d2 * d2 + d3 * d3;
    }
    __shared__ float red[4];
    for (int off = 32; off > 0; off >>= 1) s += __shfl_down(s, off, 64);
    const int lane = threadIdx.x & 63;
    const int wid = threadIdx.x >> 6;
    if (lane == 0) red[wid] = s;
    __syncthreads();
    if (threadIdx.x == 0) {
        float t = red[0] + red[1] + red[2] + red[3];
        atomicAdd(outs, t * inv_total);
    }
}

// ---------------- host ----------------
extern "C" void kernel_launch(void* const* d_in, const int* in_sizes, int n_in,
                              void* d_out, int out_size, void* d_ws, size_t ws_size,
                              hipStream_t stream) {
    const float* X      = (const float*)d_in[0];
    const int*   ei1    = (const int*)d_in[1];
    const int*   ei2    = (const int*)d_in[2];
    const int*   t_p    = (const int*)d_in[3];
    const float* noise1 = (const float*)d_in[4];
    const float* noise2 = (const float*)d_in[5];
    const float* encW1  = (const float*)d_in[6];
    const float* encb1  = (const float*)d_in[7];
    const float* encW2  = (const float*)d_in[8];
    const float* encb2  = (const float*)d_in[9];
    const float* tmW1   = (const float*)d_in[10];
    const float* tmb1   = (const float*)d_in[11];
    const float* tmW2   = (const float*)d_in[12];
    const float* tmb2   = (const float*)d_in[13];
    const float* g1W    = (const float*)d_in[14];
    const float* g1b    = (const float*)d_in[15];
    const float* g2W    = (const float*)d_in[16];
    const float* g2b    = (const float*)d_in[17];
    const float* g3W    = (const float*)d_in[18];
    const float* g3b    = (const float*)d_in[19];

    float* out_hdiff = (float*)d_out;
    float* out_L     = (float*)d_out + (size_t)NN * 128;

    char* p = (char*)d_ws;
    auto alloc = [&](size_t bytes) -> void* {
        void* r = (void*)p;
        p += (bytes + 255) & ~(size_t)255;
        return r;
    };
    int* cnts = (int*)alloc((size_t)4 * NN * sizeof(int));
    int *cnt1 = cnts, *cnt2 = cnts + NN, *fill1 = cnts + 2 * NN, *fill2 = cnts + 3 * NN;
    int* rowptr1 = (int*)alloc((NN + 1) * sizeof(int));
    int* rowptr2 = (int*)alloc((NN + 1) * sizeof(int));
    int* col1    = (int*)alloc((size_t)NE * sizeof(int));
    int* col2    = (int*)alloc((size_t)NE * sizeof(int));
    float* dinv1 = (float*)alloc(NN * sizeof(float));
    float* dinv2 = (float*)alloc(NN * sizeof(float));
    float* scal  = (float*)alloc(256 * sizeof(float));  // [0]=sa [1]=sm [2..129]=cvec
    unsigned short* WtS = (unsigned short*)alloc((size_t)6 * 16384 * sizeof(unsigned short));
    const size_t FB = (size_t)NN * 128;
    unsigned short* Xb = (unsigned short*)alloc(FB * 2);  // also V1d
    unsigned short* A1 = (unsigned short*)alloc(FB * 2);  // enc act v1, then h_t_v1
    unsigned short* A2 = (unsigned short*)alloc(FB * 2);  // enc act v2, then h_t_v2
    unsigned short* D0 = (unsigned short*)alloc(FB * 2);  // GEMM->agg scratch (unit0)
    unsigned short* D1 = (unsigned short*)alloc(FB * 2);  // GEMM->agg scratch (unit1)
    unsigned short* F1 = (unsigned short*)alloc(FB * 2);  // h0_v1, then pred_v1
    unsigned short* F2 = (unsigned short*)alloc(FB * 2);  // h0_v2, then V2d, then pred_v2
    unsigned short* V1d = Xb;
    unsigned short* V2d = F2;

    const unsigned short* W_enc1 = WtS;
    const unsigned short* W_enc2 = WtS + 1 * 16384;
    const unsigned short* W_g1a  = WtS + 2 * 16384;
    const unsigned short* W_g1b  = WtS + 3 * 16384;
    const unsigned short* W_g2   = WtS + 4 * 16384;
    const unsigned short* W_g3   = WtS + 5 * 16384;

    const int* src1 = ei1;
    const int* dst1 = ei1 + NE;
    const int* src2 = ei2;
    const int* dst2 = ei2 + NE;

    const int nbE2  = divup(2 * NE, 256);
    const int nbAgg = divup(2 * NN, 4);  // 25000 blocks (4 waves/block)
    const int total2 = NN * 64;

    // --- preprocessing (5 dispatches) ---
    k_prep<<<2048, 256, 0, stream>>>(X, encW1, encW2, g1W, g2W, g3W, cnts, Xb, WtS);
    k_scalars<<<1, 128, 0, stream>>>(t_p, tmW1, tmb1, tmW2, tmb2, g1W, scal, out_L);
    k_hist2<<<nbE2, 256, 0, stream>>>(dst1, dst2, cnt1, cnt2);
    k_scanfull<<<1, 1024, 0, stream>>>(cnts, rowptr1, rowptr2, dinv1, dinv2);
    k_fill2<<<nbE2, 256, 0, stream>>>(src1, dst1, src2, dst2, rowptr1, rowptr2,
                                      fill1, fill2, col1, col2);

    // --- encoder layer 1: shared GEMM, dual agg ---
    k_mgemm2<<<NBG, 256, 0, stream>>>(Xb, nullptr, D0, nullptr, nullptr, nullptr,
                                      W_enc1, nullptr, nullptr);
    k_agg2<<<nbAgg, 256, 0, stream>>>(D0, D0, rowptr1, col1, dinv1, rowptr2, col2, dinv2,
                                      encb1, A1, A2, 1);
    // --- encoder layer 2 ---
    k_mgemm2<<<2 * NBG, 256, 0, stream>>>(A1, nullptr, D0, A2, nullptr, D1,
                                          W_enc2, nullptr, nullptr);
    k_agg2<<<nbAgg, 256, 0, stream>>>(D0, D1, rowptr1, col1, dinv1, rowptr2, col2, dinv2,
                                      encb2, F1, F2, 0);  // h0_v1, h0_v2

    // --- h_diff out (f32) + h_t (bf16 into A1/A2) ---
    k_mix<<<2048, 256, 0, stream>>>(F1, F2, noise1, noise2, scal, out_hdiff, A1, A2, total2);

    // --- denoiser layer 1 (dual GEMM + cvec, cross inputs) ---
    k_mgemm2<<<2 * NBG, 256, 0, stream>>>(A1, A2, D0, A2, A1, D1, W_g1a, W_g1b, scal + 2);
    k_agg2<<<nbAgg, 256, 0, stream>>>(D0, D1, rowptr1, col1, dinv1, rowptr2, col2, dinv2,
                                      g1b, V1d, V2d, 1);
    // --- denoiser layer 2 ---
    k_mgemm2<<<2 * NBG, 256, 0, stream>>>(V1d, nullptr, D0, V2d, nullptr, D1,
                                          W_g2, nullptr, nullptr);
    k_agg2<<<nbAgg, 256, 0, stream>>>(D0, D1, rowptr1, col1, dinv1, rowptr2, col2, dinv2,
                                      g2b, V1d, V2d, 1);
    // --- denoiser layer 3 ---
    k_mgemm2<<<2 * NBG, 256, 0, stream>>>(V1d, nullptr, D0, V2d, nullptr, D1,
                                          W_g3, nullptr, nullptr);
    k_agg2<<<nbAgg, 256, 0, stream>>>(D0, D1, rowptr1, col1, dinv1, rowptr2, col2, dinv2,
                                      g3b, F1, F2, 0);  // pred_v1, pred_v2

    // --- loss ---
    k_loss<<<2048, 256, 0, stream>>>(F1, F2, noise1, noise2, out_L, total2,
                                     1.0f / (float)((size_t)NN * 128));
}

// Round 12
// 692.073 us; speedup vs baseline: 1.3096x; 1.3096x over previous
//
#include <hip/hip_runtime.h>

#define NN 50000
#define NE 600000
#define NBG 782  // divup(NN,64)

typedef __attribute__((ext_vector_type(8))) short short8;
typedef __attribute__((ext_vector_type(4))) float f32x4;

static inline int divup(int a, int b) { return (a + b - 1) / b; }

__device__ inline unsigned short f2bf(float f) {
    unsigned int u = __float_as_uint(f);
    unsigned int r = (u + 0x7FFFu + ((u >> 16) & 1u)) >> 16;
    return (unsigned short)r;
}
__device__ inline float bflo(unsigned int u) { return __uint_as_float(u << 16); }
__device__ inline float bfhi(unsigned int u) { return __uint_as_float(u & 0xFFFF0000u); }

// ---------------- fused prep: zero counters + X->bf16 cast + weight prep ----------------
#define PREP_Z (4 * NN)
#define PREP_X (NN * 32)
#define PREP_W (6 * 16384)
__global__ void k_prep(const float* __restrict__ X,
                       const float* __restrict__ encW1, const float* __restrict__ encW2,
                       const float* __restrict__ g1W, const float* __restrict__ g2W,
                       const float* __restrict__ g3W,
                       int* __restrict__ cnts, unsigned short* __restrict__ Xb,
                       unsigned short* __restrict__ WtS) {
    int i = blockIdx.x * blockDim.x + threadIdx.x;
    const int stride = gridDim.x * blockDim.x;
    const int T = PREP_Z + PREP_X + PREP_W;
    for (; i < T; i += stride) {
        if (i < PREP_Z) {
            cnts[i] = 0;
        } else if (i < PREP_Z + PREP_X) {
            int j = i - PREP_Z;
            float4 v = ((const float4*)X)[j];
            ushort4 o;
            o.x = f2bf(v.x); o.y = f2bf(v.y); o.z = f2bf(v.z); o.w = f2bf(v.w);
            ((ushort4*)Xb)[j] = o;
        } else {
            // W^T bf16, XOR-swizzled: elem (n,k) at byte ((n<<8)|(k<<1)) ^ ((n&7)<<4)
            int j = i - (PREP_Z + PREP_X);
            int m = j >> 14;
            int r = j & 16383;
            int k = r >> 7;
            int n = r & 127;
            const float* src;
            switch (m) {
                case 0: src = encW1; break;
                case 1: src = encW2; break;
                case 2: src = g1W; break;
                case 3: src = g1W + 16384; break;
                case 4: src = g2W; break;
                default: src = g3W; break;
            }
            unsigned short v = f2bf(src[k * 128 + n]);
            unsigned int byte = (((unsigned)n << 8) | ((unsigned)k << 1)) ^ (((unsigned)n & 7u) << 4);
            WtS[(m << 14) + (byte >> 1)] = v;
        }
    }
}

// scalars: sqrt_ab, sqrt_1m, cvec[128] = temb @ g1_W[256:384,:], zero L out
__global__ void k_scalars(const int* __restrict__ t_p,
                          const float* __restrict__ tmW1, const float* __restrict__ tmb1,
                          const float* __restrict__ tmW2, const float* __restrict__ tmb2,
                          const float* __restrict__ g1W,
                          float* __restrict__ scal, float* __restrict__ lout) {
    __shared__ float e32[32];
    __shared__ float temb[128];
    const int tid = threadIdx.x;
    const int t = t_p[0];
    if (tid < 32) {
        float x = (float)t * tmW1[tid] + tmb1[tid];
        e32[tid] = x / (1.0f + expf(-x));  // silu
    }
    __syncthreads();
    float acc = tmb2[tid];
    for (int j = 0; j < 32; ++j) acc += e32[j] * tmW2[j * 128 + tid];
    temb[tid] = acc;
    __syncthreads();
    float cv = 0.0f;
    for (int j = 0; j < 128; ++j) cv += temb[j] * g1W[(256 + j) * 128 + tid];
    scal[2 + tid] = cv;
    if (tid == 0) {
        double ab = 1.0;
        for (int i = 0; i <= t; ++i) {
            double beta = 1e-4 + (0.02 - 1e-4) * (double)i / 99.0;
            ab *= (1.0 - beta);
        }
        scal[0] = (float)sqrt(ab);
        scal[1] = (float)sqrt(1.0 - ab);
        lout[0] = 0.0f;
    }
}

// both graphs' degree histograms in one dispatch
__global__ void k_hist2(const int* __restrict__ dst1, const int* __restrict__ dst2,
                        int* __restrict__ cnt1, int* __restrict__ cnt2) {
    int i = blockIdx.x * blockDim.x + threadIdx.x;
    if (i < NE) atomicAdd(&cnt1[dst1[i]], 1);
    else if (i < 2 * NE) atomicAdd(&cnt2[dst2[i - NE]], 1);
}

// ---------------- hierarchical scan over cnts[0..2N) ----------------
#define SCAN_B 256
__global__ void k_scan1(const int* __restrict__ cnt, int* __restrict__ exc,
                        int* __restrict__ bsum, int n) {
    __shared__ int s[SCAN_B];
    int i = blockIdx.x * SCAN_B + threadIdx.x;
    int v = (i < n) ? cnt[i] : 0;
    s[threadIdx.x] = v;
    __syncthreads();
    for (int off = 1; off < SCAN_B; off <<= 1) {
        int tv = (threadIdx.x >= off) ? s[threadIdx.x - off] : 0;
        __syncthreads();
        s[threadIdx.x] += tv;
        __syncthreads();
    }
    if (i < n) exc[i] = s[threadIdx.x] - v;
    if (threadIdx.x == SCAN_B - 1) bsum[blockIdx.x] = s[SCAN_B - 1];
}

__global__ __launch_bounds__(512) void k_scan2(int* __restrict__ bsum, int nb) {
    __shared__ int s[512];
    int v = (threadIdx.x < nb) ? bsum[threadIdx.x] : 0;
    s[threadIdx.x] = v;
    __syncthreads();
    for (int off = 1; off < 512; off <<= 1) {
        int tv = (threadIdx.x >= off) ? s[threadIdx.x - off] : 0;
        __syncthreads();
        s[threadIdx.x] += tv;
        __syncthreads();
    }
    if (threadIdx.x < nb) bsum[threadIdx.x] = s[threadIdx.x] - v;
}

// finalize: rowptr1/rowptr2 (with -NE shift for graph2) + dinv from cnt
__global__ void k_scan3(const int* __restrict__ exc, const int* __restrict__ bsum,
                        const int* __restrict__ cnt,
                        int* __restrict__ rowptr1, int* __restrict__ rowptr2,
                        float* __restrict__ dinv1, float* __restrict__ dinv2) {
    int i = blockIdx.x * SCAN_B + threadIdx.x;
    if (i < 2 * NN) {
        int e = exc[i] + bsum[blockIdx.x];
        int c = cnt[i];
        if (i < NN) {
            rowptr1[i] = e;
            dinv1[i] = rsqrtf((float)c + 1.0f);
        } else {
            rowptr2[i - NN] = e - NE;
            dinv2[i - NN] = rsqrtf((float)c + 1.0f);
        }
    }
    if (i == 0) { rowptr1[NN] = NE; rowptr2[NN] = NE; }
}

// both graphs' CSR fill in one dispatch
__global__ void k_fill2(const int* __restrict__ src1, const int* __restrict__ dst1,
                        const int* __restrict__ src2, const int* __restrict__ dst2,
                        const int* __restrict__ rowptr1, const int* __restrict__ rowptr2,
                        int* __restrict__ fill1, int* __restrict__ fill2,
                        int* __restrict__ col1, int* __restrict__ col2) {
    int i = blockIdx.x * blockDim.x + threadIdx.x;
    if (i < NE) {
        int d = dst1[i];
        int p = atomicAdd(&fill1[d], 1);
        col1[rowptr1[d] + p] = src1[i];
    } else if (i < 2 * NE) {
        int j = i - NE;
        int d = dst2[j];
        int p = atomicAdd(&fill2[d], 1);
        col2[rowptr2[d] + p] = src2[j];
    }
}

// ---------------- combined MFMA GEMM (two units) ----------------
// unit u: out_u = A_u@Wa (+ B_u@Wb) (+ cvec).  Wa/Wb: swizzled 32KB W^T images.
// Block: 64 rows, 4 waves; wave = 16 rows x 128 cols; 16x16x32 MFMA.
__global__ __launch_bounds__(256) void k_mgemm2(
    const unsigned short* __restrict__ A0, const unsigned short* __restrict__ B0,
    unsigned short* __restrict__ out0,
    const unsigned short* __restrict__ A1, const unsigned short* __restrict__ B1,
    unsigned short* __restrict__ out1,
    const unsigned short* __restrict__ Wa, const unsigned short* __restrict__ Wb,
    const float* __restrict__ cvec) {
    __shared__ unsigned short sW[16384];  // 32KB swizzled W^T
    const int unit = blockIdx.x / NBG;
    const int blk = blockIdx.x - unit * NBG;
    const unsigned short* A = unit ? A1 : A0;
    const unsigned short* B = unit ? B1 : B0;
    unsigned short* out = unit ? out1 : out0;

    const int tid = threadIdx.x;
    const int wv = tid >> 6;
    const int l = tid & 63;
    const int lrow = l & 15;   // A-row / C-col within tile
    const int lk = l >> 4;     // 0..3: K-subgroup / C-row-group
    const int r0 = blk * 64 + wv * 16;

    f32x4 acc[8];
#pragma unroll
    for (int ct = 0; ct < 8; ++ct) acc[ct] = (f32x4){0.f, 0.f, 0.f, 0.f};

    const unsigned short* Aptr[2] = {A, B};
    const unsigned short* Wptr[2] = {Wa, Wb};
    const int np = (B != nullptr) ? 2 : 1;

    int arow = r0 + lrow;
    if (arow >= NN) arow = NN - 1;

    for (int p = 0; p < np; ++p) {
        __syncthreads();  // protect sW from previous pass readers
        {
            const uint4* s = (const uint4*)Wptr[p];
            uint4* d = (uint4*)sW;
#pragma unroll
            for (int j = 0; j < 8; ++j) d[tid + j * 256] = s[tid + j * 256];
        }
        __syncthreads();
        const unsigned short* abase = Aptr[p] + (size_t)arow * 128 + lk * 8;
#pragma unroll
        for (int ks = 0; ks < 4; ++ks) {
            short8 af = *(const short8*)(abase + ks * 32);
            const int kb2 = (lk * 8 + ks * 32) << 1;  // byte offset of k-base
#pragma unroll
            for (int ct = 0; ct < 8; ++ct) {
                int n = ct * 16 + lrow;
                int byteoff = ((n << 8) + kb2) ^ ((l & 7) << 4);
                short8 bf = *(const short8*)((const char*)sW + byteoff);
                acc[ct] = __builtin_amdgcn_mfma_f32_16x16x32_bf16(af, bf, acc[ct], 0, 0, 0);
            }
        }
    }
    // epilogue: C[row = r0 + lk*4 + reg][col = ct*16 + lrow]
#pragma unroll
    for (int ct = 0; ct < 8; ++ct) {
        float cv = cvec ? cvec[ct * 16 + lrow] : 0.0f;
#pragma unroll
        for (int rg = 0; rg < 4; ++rg) {
            int row = r0 + lk * 4 + rg;
            if (row < NN) out[(size_t)row * 128 + ct * 16 + lrow] = f2bf(acc[ct][rg] + cv);
        }
    }
}

// ---------------- combined GCN aggregation (two units, bf16 in/out) ----------------
// wave w<NN: graph1 on in0->out0; else graph2 on in1->out1.
// Quarter-wave (16 lanes x 16B) per gathered row, 2-deep pipelined gather.
__global__ __launch_bounds__(256) void k_agg2(
    const unsigned short* __restrict__ in0, const unsigned short* __restrict__ in1,
    const int* __restrict__ rowptr1, const int* __restrict__ col1, const float* __restrict__ dinv1,
    const int* __restrict__ rowptr2, const int* __restrict__ col2, const float* __restrict__ dinv2,
    const float* __restrict__ bias,
    unsigned short* __restrict__ out0, unsigned short* __restrict__ out1, int do_relu) {
    const int gw = (blockIdx.x * blockDim.x + threadIdx.x) >> 6;
    if (gw >= 2 * NN) return;
    const int unit = gw >= NN;
    const int d = unit ? gw - NN : gw;
    const unsigned short* h = unit ? in1 : in0;
    const int* rowptr = unit ? rowptr2 : rowptr1;
    const int* colA = unit ? col2 : col1;
    const float* dinv = unit ? dinv2 : dinv1;
    unsigned short* out = unit ? out1 : out0;

    const int l = threadIdx.x & 63;
    const int lg = l >> 4;   // quarter-wave group 0..3
    const int ll = l & 15;   // owns features ll*8..ll*8+7
    const float di = dinv[d];

    float acc[8];
#pragma unroll
    for (int k = 0; k < 8; ++k) acc[k] = 0.0f;

    const int e0 = rowptr[d];
    const int e1 = rowptr[d + 1];
    for (int base = e0; base < e1; base += 64) {
        int cnt = min(64, e1 - base);
        int cs = 0;
        float ws = 0.0f;
        if (base + l < e1) {
            cs = colA[base + l];
            ws = dinv[cs];
        }
        // 2-deep pipelined gather: prefetch next 4-edge group before consuming current
        int s0 = __shfl(cs, lg);
        float w0 = __shfl(ws, lg);
        uint4 u0 = *((const uint4*)(h + (size_t)s0 * 128) + ll);
        for (int j4 = 4; j4 < cnt; j4 += 4) {
            int s1 = __shfl(cs, j4 + lg);
            float w1 = __shfl(ws, j4 + lg);
            uint4 u1 = *((const uint4*)(h + (size_t)s1 * 128) + ll);
            acc[0] += w0 * bflo(u0.x);
            acc[1] += w0 * bfhi(u0.x);
            acc[2] += w0 * bflo(u0.y);
            acc[3] += w0 * bfhi(u0.y);
            acc[4] += w0 * bflo(u0.z);
            acc[5] += w0 * bfhi(u0.z);
            acc[6] += w0 * bflo(u0.w);
            acc[7] += w0 * bfhi(u0.w);
            u0 = u1;
            w0 = w1;
        }
        acc[0] += w0 * bflo(u0.x);
        acc[1] += w0 * bfhi(u0.x);
        acc[2] += w0 * bflo(u0.y);
        acc[3] += w0 * bfhi(u0.y);
        acc[4] += w0 * bflo(u0.z);
        acc[5] += w0 * bfhi(u0.z);
        acc[6] += w0 * bflo(u0.w);
        acc[7] += w0 * bfhi(u0.w);
    }
    // combine the 4 groups
#pragma unroll
    for (int k = 0; k < 8; ++k) {
        acc[k] += __shfl_xor(acc[k], 16);
        acc[k] += __shfl_xor(acc[k], 32);
    }
    if (lg == 0) {
        uint4 su = *((const uint4*)(h + (size_t)d * 128) + ll);
        float4 b0 = ((const float4*)bias)[ll * 2];
        float4 b1 = ((const float4*)bias)[ll * 2 + 1];
        float sf[8] = {bflo(su.x), bfhi(su.x), bflo(su.y), bfhi(su.y),
                       bflo(su.z), bfhi(su.z), bflo(su.w), bfhi(su.w)};
        float bb[8] = {b0.x, b0.y, b0.z, b0.w, b1.x, b1.y, b1.z, b1.w};
        unsigned short o[8];
#pragma unroll
        for (int k = 0; k < 8; ++k) {
            float v = di * (acc[k] + di * sf[k]) + bb[k];
            if (do_relu) v = fmaxf(v, 0.0f);
            o[k] = f2bf(v);
        }
        uint4 ov;
        ov.x = (unsigned int)o[0] | ((unsigned int)o[1] << 16);
        ov.y = (unsigned int)o[2] | ((unsigned int)o[3] << 16);
        ov.z = (unsigned int)o[4] | ((unsigned int)o[5] << 16);
        ov.w = (unsigned int)o[6] | ((unsigned int)o[7] << 16);
        *((uint4*)(out + (size_t)d * 128) + ll) = ov;
    }
}

// ---------------- h_diff (f32 out) + h_t (bf16) ----------------
__global__ void k_mix(const unsigned short* __restrict__ F1, const unsigned short* __restrict__ F2,
                      const float* __restrict__ n1, const float* __restrict__ n2,
                      const float* __restrict__ scal, float* __restrict__ hdiff,
                      unsigned short* __restrict__ B1, unsigned short* __restrict__ B2, int total2) {
    const float sa = scal[0];
    const float sm = scal[1];
    int i = blockIdx.x * blockDim.x + threadIdx.x;
    const int stride = gridDim.x * blockDim.x;
    for (; i < total2; i += stride) {
        unsigned int u1 = ((const unsigned int*)F1)[i];
        unsigned int u2 = ((const unsigned int*)F2)[i];
        float a0 = bflo(u1), a1 = bfhi(u1);
        float b0 = bflo(u2), b1 = bfhi(u2);
        float2 x = ((const float2*)n1)[i];
        float2 y = ((const float2*)n2)[i];
        float2 hd;
        hd.x = 0.5f * (a0 + b0);
        hd.y = 0.5f * (a1 + b1);
        ((float2*)hdiff)[i] = hd;
        float h1x = sa * a0 + sm * x.x, h1y = sa * a1 + sm * x.y;
        float h2x = sa * b0 + sm * y.x, h2y = sa * b1 + sm * y.y;
        ((unsigned int*)B1)[i] = (unsigned int)f2bf(h1x) | ((unsigned int)f2bf(h1y) << 16);
        ((unsigned int*)B2)[i] = (unsigned int)f2bf(h2x) | ((unsigned int)f2bf(h2y) << 16);
    }
}

// ---------------- L_diff ----------------
__global__ void k_loss(const unsigned short* __restrict__ P1, const unsigned short* __restrict__ P2,
                       const float* __restrict__ n1, const float* __restrict__ n2,
                       float* __restrict__ outs, int total2, float inv_total) {
    float s = 0.0f;
    int i = blockIdx.x * blockDim.x + threadIdx.x;
    const int stride = gridDim.x * blockDim.x;
    for (; i < total2; i += stride) {
        unsigned int u1 = ((const unsigned int*)P1)[i];
        unsigned int u2 = ((const unsigned int*)P2)[i];
        float2 x = ((const float2*)n1)[i];
        float2 y = ((const float2*)n2)[i];
        float d0 = bflo(u1) - x.x, d1 = bfhi(u1) - x.y;
        float d2 = bflo(u2) - y.x, d3 = bfhi(u2) - y.y;
        s += d0 * d0 + d1 * d1 + d2 * d2 + d3 * d3;
    }
    __shared__ float red[4];
    for (int off = 32; off > 0; off >>= 1) s += __shfl_down(s, off, 64);
    const int lane = threadIdx.x & 63;
    const int wid = threadIdx.x >> 6;
    if (lane == 0) red[wid] = s;
    __syncthreads();
    if (threadIdx.x == 0) {
        float t = red[0] + red[1] + red[2] + red[3];
        atomicAdd(outs, t * inv_total);
    }
}

// ---------------- host ----------------
extern "C" void kernel_launch(void* const* d_in, const int* in_sizes, int n_in,
                              void* d_out, int out_size, void* d_ws, size_t ws_size,
                              hipStream_t stream) {
    const float* X      = (const float*)d_in[0];
    const int*   ei1    = (const int*)d_in[1];
    const int*   ei2    = (const int*)d_in[2];
    const int*   t_p    = (const int*)d_in[3];
    const float* noise1 = (const float*)d_in[4];
    const float* noise2 = (const float*)d_in[5];
    const float* encW1  = (const float*)d_in[6];
    const float* encb1  = (const float*)d_in[7];
    const float* encW2  = (const float*)d_in[8];
    const float* encb2  = (const float*)d_in[9];
    const float* tmW1   = (const float*)d_in[10];
    const float* tmb1   = (const float*)d_in[11];
    const float* tmW2   = (const float*)d_in[12];
    const float* tmb2   = (const float*)d_in[13];
    const float* g1W    = (const float*)d_in[14];
    const float* g1b    = (const float*)d_in[15];
    const float* g2W    = (const float*)d_in[16];
    const float* g2b    = (const float*)d_in[17];
    const float* g3W    = (const float*)d_in[18];
    const float* g3b    = (const float*)d_in[19];

    float* out_hdiff = (float*)d_out;
    float* out_L     = (float*)d_out + (size_t)NN * 128;

    char* p = (char*)d_ws;
    auto alloc = [&](size_t bytes) -> void* {
        void* r = (void*)p;
        p += (bytes + 255) & ~(size_t)255;
        return r;
    };
    int* cnts = (int*)alloc((size_t)4 * NN * sizeof(int));
    int *cnt1 = cnts, *cnt2 = cnts + NN, *fill1 = cnts + 2 * NN, *fill2 = cnts + 3 * NN;
    int* rowptr1 = (int*)alloc((NN + 1) * sizeof(int));
    int* rowptr2 = (int*)alloc((NN + 1) * sizeof(int));
    int* exc     = (int*)alloc((size_t)2 * NN * sizeof(int));
    int* bsum    = (int*)alloc(512 * sizeof(int));
    int* col1    = (int*)alloc((size_t)NE * sizeof(int));
    int* col2    = (int*)alloc((size_t)NE * sizeof(int));
    float* dinv1 = (float*)alloc(NN * sizeof(float));
    float* dinv2 = (float*)alloc(NN * sizeof(float));
    float* scal  = (float*)alloc(256 * sizeof(float));  // [0]=sa [1]=sm [2..129]=cvec
    unsigned short* WtS = (unsigned short*)alloc((size_t)6 * 16384 * sizeof(unsigned short));
    const size_t FB = (size_t)NN * 128;
    unsigned short* Xb = (unsigned short*)alloc(FB * 2);  // also V1d
    unsigned short* A1 = (unsigned short*)alloc(FB * 2);  // enc act v1, then h_t_v1
    unsigned short* A2 = (unsigned short*)alloc(FB * 2);  // enc act v2, then h_t_v2
    unsigned short* D0 = (unsigned short*)alloc(FB * 2);  // GEMM->agg scratch (unit0)
    unsigned short* D1 = (unsigned short*)alloc(FB * 2);  // GEMM->agg scratch (unit1)
    unsigned short* F1 = (unsigned short*)alloc(FB * 2);  // h0_v1, then pred_v1
    unsigned short* F2 = (unsigned short*)alloc(FB * 2);  // h0_v2, then V2d, then pred_v2
    unsigned short* V1d = Xb;
    unsigned short* V2d = F2;

    const unsigned short* W_enc1 = WtS;
    const unsigned short* W_enc2 = WtS + 1 * 16384;
    const unsigned short* W_g1a  = WtS + 2 * 16384;
    const unsigned short* W_g1b  = WtS + 3 * 16384;
    const unsigned short* W_g2   = WtS + 4 * 16384;
    const unsigned short* W_g3   = WtS + 5 * 16384;

    const int* src1 = ei1;
    const int* dst1 = ei1 + NE;
    const int* src2 = ei2;
    const int* dst2 = ei2 + NE;

    const int nbE2   = divup(2 * NE, 256);
    const int nbAgg  = divup(2 * NN, 4);      // 25000 blocks (4 waves/block)
    const int nbScan = divup(2 * NN, SCAN_B); // 391
    const int total2 = NN * 64;

    // --- preprocessing (7 dispatches) ---
    k_prep<<<2048, 256, 0, stream>>>(X, encW1, encW2, g1W, g2W, g3W, cnts, Xb, WtS);
    k_scalars<<<1, 128, 0, stream>>>(t_p, tmW1, tmb1, tmW2, tmb2, g1W, scal, out_L);
    k_hist2<<<nbE2, 256, 0, stream>>>(dst1, dst2, cnt1, cnt2);
    k_scan1<<<nbScan, 256, 0, stream>>>(cnts, exc, bsum, 2 * NN);
    k_scan2<<<1, 512, 0, stream>>>(bsum, nbScan);
    k_scan3<<<nbScan, 256, 0, stream>>>(exc, bsum, cnts, rowptr1, rowptr2, dinv1, dinv2);
    k_fill2<<<nbE2, 256, 0, stream>>>(src1, dst1, src2, dst2, rowptr1, rowptr2,
                                      fill1, fill2, col1, col2);

    // --- encoder layer 1: shared GEMM, dual agg ---
    k_mgemm2<<<NBG, 256, 0, stream>>>(Xb, nullptr, D0, nullptr, nullptr, nullptr,
                                      W_enc1, nullptr, nullptr);
    k_agg2<<<nbAgg, 256, 0, stream>>>(D0, D0, rowptr1, col1, dinv1, rowptr2, col2, dinv2,
                                      encb1, A1, A2, 1);
    // --- encoder layer 2 ---
    k_mgemm2<<<2 * NBG, 256, 0, stream>>>(A1, nullptr, D0, A2, nullptr, D1,
                                          W_enc2, nullptr, nullptr);
    k_agg2<<<nbAgg, 256, 0, stream>>>(D0, D1, rowptr1, col1, dinv1, rowptr2, col2, dinv2,
                                      encb2, F1, F2, 0);  // h0_v1, h0_v2

    // --- h_diff out (f32) + h_t (bf16 into A1/A2) ---
    k_mix<<<2048, 256, 0, stream>>>(F1, F2, noise1, noise2, scal, out_hdiff, A1, A2, total2);

    // --- denoiser layer 1 (dual GEMM + cvec, cross inputs) ---
    k_mgemm2<<<2 * NBG, 256, 0, stream>>>(A1, A2, D0, A2, A1, D1, W_g1a, W_g1b, scal + 2);
    k_agg2<<<nbAgg, 256, 0, stream>>>(D0, D1, rowptr1, col1, dinv1, rowptr2, col2, dinv2,
                                      g1b, V1d, V2d, 1);
    // --- denoiser layer 2 ---
    k_mgemm2<<<2 * NBG, 256, 0, stream>>>(V1d, nullptr, D0, V2d, nullptr, D1,
                                          W_g2, nullptr, nullptr);
    k_agg2<<<nbAgg, 256, 0, stream>>>(D0, D1, rowptr1, col1, dinv1, rowptr2, col2, dinv2,
                                      g2b, V1d, V2d, 1);
    // --- denoiser layer 3 ---
    k_mgemm2<<<2 * NBG, 256, 0, stream>>>(V1d, nullptr, D0, V2d, nullptr, D1,
                                          W_g3, nullptr, nullptr);
    k_agg2<<<nbAgg, 256, 0, stream>>>(D0, D1, rowptr1, col1, dinv1, rowptr2, col2, dinv2,
                                      g3b, F1, F2, 0);  // pred_v1, pred_v2

    // --- loss ---
    k_loss<<<2048, 256, 0, stream>>>(F1, F2, noise1, noise2, out_L, total2,
                                     1.0f / (float)((size_t)NN * 128));
}

// Round 13
// 681.661 us; speedup vs baseline: 1.3296x; 1.0153x over previous
//
#include <hip/hip_runtime.h>

#define NN 50000
#define NE 600000
#define NBG 782  // divup(NN,64)

typedef __attribute__((ext_vector_type(8))) short short8;
typedef __attribute__((ext_vector_type(4))) float f32x4;

static inline int divup(int a, int b) { return (a + b - 1) / b; }

__device__ inline unsigned short f2bf(float f) {
    unsigned int u = __float_as_uint(f);
    unsigned int r = (u + 0x7FFFu + ((u >> 16) & 1u)) >> 16;
    return (unsigned short)r;
}
__device__ inline float bflo(unsigned int u) { return __uint_as_float(u << 16); }
__device__ inline float bfhi(unsigned int u) { return __uint_as_float(u & 0xFFFF0000u); }

// ---------------- fused prep: zero counters + X->bf16 cast + weight prep ----------------
#define PREP_Z (4 * NN)
#define PREP_X (NN * 32)
#define PREP_W (6 * 16384)
__global__ void k_prep(const float* __restrict__ X,
                       const float* __restrict__ encW1, const float* __restrict__ encW2,
                       const float* __restrict__ g1W, const float* __restrict__ g2W,
                       const float* __restrict__ g3W,
                       int* __restrict__ cnts, unsigned short* __restrict__ Xb,
                       unsigned short* __restrict__ WtS) {
    int i = blockIdx.x * blockDim.x + threadIdx.x;
    const int stride = gridDim.x * blockDim.x;
    const int T = PREP_Z + PREP_X + PREP_W;
    for (; i < T; i += stride) {
        if (i < PREP_Z) {
            cnts[i] = 0;
        } else if (i < PREP_Z + PREP_X) {
            int j = i - PREP_Z;
            float4 v = ((const float4*)X)[j];
            ushort4 o;
            o.x = f2bf(v.x); o.y = f2bf(v.y); o.z = f2bf(v.z); o.w = f2bf(v.w);
            ((ushort4*)Xb)[j] = o;
        } else {
            // W^T bf16, XOR-swizzled: elem (n,k) at byte ((n<<8)|(k<<1)) ^ ((n&7)<<4)
            int j = i - (PREP_Z + PREP_X);
            int m = j >> 14;
            int r = j & 16383;
            int k = r >> 7;
            int n = r & 127;
            const float* src;
            switch (m) {
                case 0: src = encW1; break;
                case 1: src = encW2; break;
                case 2: src = g1W; break;
                case 3: src = g1W + 16384; break;
                case 4: src = g2W; break;
                default: src = g3W; break;
            }
            unsigned short v = f2bf(src[k * 128 + n]);
            unsigned int byte = (((unsigned)n << 8) | ((unsigned)k << 1)) ^ (((unsigned)n & 7u) << 4);
            WtS[(m << 14) + (byte >> 1)] = v;
        }
    }
}

// scalars: sqrt_ab, sqrt_1m, cvec[128] = temb @ g1_W[256:384,:], zero L out
__global__ void k_scalars(const int* __restrict__ t_p,
                          const float* __restrict__ tmW1, const float* __restrict__ tmb1,
                          const float* __restrict__ tmW2, const float* __restrict__ tmb2,
                          const float* __restrict__ g1W,
                          float* __restrict__ scal, float* __restrict__ lout) {
    __shared__ float e32[32];
    __shared__ float temb[128];
    const int tid = threadIdx.x;
    const int t = t_p[0];
    if (tid < 32) {
        float x = (float)t * tmW1[tid] + tmb1[tid];
        e32[tid] = x / (1.0f + expf(-x));  // silu
    }
    __syncthreads();
    float acc = tmb2[tid];
    for (int j = 0; j < 32; ++j) acc += e32[j] * tmW2[j * 128 + tid];
    temb[tid] = acc;
    __syncthreads();
    float cv = 0.0f;
    for (int j = 0; j < 128; ++j) cv += temb[j] * g1W[(256 + j) * 128 + tid];
    scal[2 + tid] = cv;
    if (tid == 0) {
        double ab = 1.0;
        for (int i = 0; i <= t; ++i) {
            double beta = 1e-4 + (0.02 - 1e-4) * (double)i / 99.0;
            ab *= (1.0 - beta);
        }
        scal[0] = (float)sqrt(ab);
        scal[1] = (float)sqrt(1.0 - ab);
        lout[0] = 0.0f;
    }
}

// both graphs' degree histograms in one dispatch
__global__ void k_hist2(const int* __restrict__ dst1, const int* __restrict__ dst2,
                        int* __restrict__ cnt1, int* __restrict__ cnt2) {
    int i = blockIdx.x * blockDim.x + threadIdx.x;
    if (i < NE) atomicAdd(&cnt1[dst1[i]], 1);
    else if (i < 2 * NE) atomicAdd(&cnt2[dst2[i - NE]], 1);
}

// ---------------- hierarchical scan over cnts[0..2N) ----------------
#define SCAN_B 256
__global__ void k_scan1(const int* __restrict__ cnt, int* __restrict__ exc,
                        int* __restrict__ bsum, int n) {
    __shared__ int s[SCAN_B];
    int i = blockIdx.x * SCAN_B + threadIdx.x;
    int v = (i < n) ? cnt[i] : 0;
    s[threadIdx.x] = v;
    __syncthreads();
    for (int off = 1; off < SCAN_B; off <<= 1) {
        int tv = (threadIdx.x >= off) ? s[threadIdx.x - off] : 0;
        __syncthreads();
        s[threadIdx.x] += tv;
        __syncthreads();
    }
    if (i < n) exc[i] = s[threadIdx.x] - v;
    if (threadIdx.x == SCAN_B - 1) bsum[blockIdx.x] = s[SCAN_B - 1];
}

__global__ __launch_bounds__(512) void k_scan2(int* __restrict__ bsum, int nb) {
    __shared__ int s[512];
    int v = (threadIdx.x < nb) ? bsum[threadIdx.x] : 0;
    s[threadIdx.x] = v;
    __syncthreads();
    for (int off = 1; off < 512; off <<= 1) {
        int tv = (threadIdx.x >= off) ? s[threadIdx.x - off] : 0;
        __syncthreads();
        s[threadIdx.x] += tv;
        __syncthreads();
    }
    if (threadIdx.x < nb) bsum[threadIdx.x] = s[threadIdx.x] - v;
}

// finalize: rowptr1/rowptr2 (with -NE shift for graph2) + dinv from cnt
__global__ void k_scan3(const int* __restrict__ exc, const int* __restrict__ bsum,
                        const int* __restrict__ cnt,
                        int* __restrict__ rowptr1, int* __restrict__ rowptr2,
                        float* __restrict__ dinv1, float* __restrict__ dinv2) {
    int i = blockIdx.x * SCAN_B + threadIdx.x;
    if (i < 2 * NN) {
        int e = exc[i] + bsum[blockIdx.x];
        int c = cnt[i];
        if (i < NN) {
            rowptr1[i] = e;
            dinv1[i] = rsqrtf((float)c + 1.0f);
        } else {
            rowptr2[i - NN] = e - NE;
            dinv2[i - NN] = rsqrtf((float)c + 1.0f);
        }
    }
    if (i == 0) { rowptr1[NN] = NE; rowptr2[NN] = NE; }
}

// both graphs' CSR fill in one dispatch
__global__ void k_fill2(const int* __restrict__ src1, const int* __restrict__ dst1,
                        const int* __restrict__ src2, const int* __restrict__ dst2,
                        const int* __restrict__ rowptr1, const int* __restrict__ rowptr2,
                        int* __restrict__ fill1, int* __restrict__ fill2,
                        int* __restrict__ col1, int* __restrict__ col2) {
    int i = blockIdx.x * blockDim.x + threadIdx.x;
    if (i < NE) {
        int d = dst1[i];
        int p = atomicAdd(&fill1[d], 1);
        col1[rowptr1[d] + p] = src1[i];
    } else if (i < 2 * NE) {
        int j = i - NE;
        int d = dst2[j];
        int p = atomicAdd(&fill2[d], 1);
        col2[rowptr2[d] + p] = src2[j];
    }
}

// ---------------- combined MFMA GEMM (two units) ----------------
// unit u: out_u = A_u@Wa (+ B_u@Wb) (+ cvec).  Wa/Wb: swizzled 32KB W^T images.
// Block: 64 rows, 4 waves; wave = 16 rows x 128 cols; 16x16x32 MFMA.
__global__ __launch_bounds__(256) void k_mgemm2(
    const unsigned short* __restrict__ A0, const unsigned short* __restrict__ B0,
    unsigned short* __restrict__ out0,
    const unsigned short* __restrict__ A1, const unsigned short* __restrict__ B1,
    unsigned short* __restrict__ out1,
    const unsigned short* __restrict__ Wa, const unsigned short* __restrict__ Wb,
    const float* __restrict__ cvec) {
    __shared__ unsigned short sW[16384];  // 32KB swizzled W^T
    const int unit = blockIdx.x / NBG;
    const int blk = blockIdx.x - unit * NBG;
    const unsigned short* A = unit ? A1 : A0;
    const unsigned short* B = unit ? B1 : B0;
    unsigned short* out = unit ? out1 : out0;

    const int tid = threadIdx.x;
    const int wv = tid >> 6;
    const int l = tid & 63;
    const int lrow = l & 15;   // A-row / C-col within tile
    const int lk = l >> 4;     // 0..3: K-subgroup / C-row-group
    const int r0 = blk * 64 + wv * 16;

    f32x4 acc[8];
#pragma unroll
    for (int ct = 0; ct < 8; ++ct) acc[ct] = (f32x4){0.f, 0.f, 0.f, 0.f};

    const unsigned short* Aptr[2] = {A, B};
    const unsigned short* Wptr[2] = {Wa, Wb};
    const int np = (B != nullptr) ? 2 : 1;

    int arow = r0 + lrow;
    if (arow >= NN) arow = NN - 1;

    for (int p = 0; p < np; ++p) {
        __syncthreads();  // protect sW from previous pass readers
        {
            const uint4* s = (const uint4*)Wptr[p];
            uint4* d = (uint4*)sW;
#pragma unroll
            for (int j = 0; j < 8; ++j) d[tid + j * 256] = s[tid + j * 256];
        }
        __syncthreads();
        const unsigned short* abase = Aptr[p] + (size_t)arow * 128 + lk * 8;
#pragma unroll
        for (int ks = 0; ks < 4; ++ks) {
            short8 af = *(const short8*)(abase + ks * 32);
            const int kb2 = (lk * 8 + ks * 32) << 1;  // byte offset of k-base
#pragma unroll
            for (int ct = 0; ct < 8; ++ct) {
                int n = ct * 16 + lrow;
                int byteoff = ((n << 8) + kb2) ^ ((l & 7) << 4);
                short8 bf = *(const short8*)((const char*)sW + byteoff);
                acc[ct] = __builtin_amdgcn_mfma_f32_16x16x32_bf16(af, bf, acc[ct], 0, 0, 0);
            }
        }
    }
    // epilogue: C[row = r0 + lk*4 + reg][col = ct*16 + lrow]
#pragma unroll
    for (int ct = 0; ct < 8; ++ct) {
        float cv = cvec ? cvec[ct * 16 + lrow] : 0.0f;
#pragma unroll
        for (int rg = 0; rg < 4; ++rg) {
            int row = r0 + lk * 4 + rg;
            if (row < NN) out[(size_t)row * 128 + ct * 16 + lrow] = f2bf(acc[ct][rg] + cv);
        }
    }
}

// ---------------- combined GCN aggregation (two units, bf16 in/out) ----------------
// wave w<NN: graph1 on in0->out0; else graph2 on in1->out1.
// Quarter-wave (16 lanes x 16B) per gathered row; 3-deep pipelined gather
// (12 edge-rows in flight per wave) with wave-uniform guards (no wasted loads).
__global__ __launch_bounds__(256) void k_agg2(
    const unsigned short* __restrict__ in0, const unsigned short* __restrict__ in1,
    const int* __restrict__ rowptr1, const int* __restrict__ col1, const float* __restrict__ dinv1,
    const int* __restrict__ rowptr2, const int* __restrict__ col2, const float* __restrict__ dinv2,
    const float* __restrict__ bias,
    unsigned short* __restrict__ out0, unsigned short* __restrict__ out1, int do_relu) {
    const int gw = (blockIdx.x * blockDim.x + threadIdx.x) >> 6;
    if (gw >= 2 * NN) return;
    const int unit = gw >= NN;
    const int d = unit ? gw - NN : gw;
    const unsigned short* h = unit ? in1 : in0;
    const int* rowptr = unit ? rowptr2 : rowptr1;
    const int* colA = unit ? col2 : col1;
    const float* dinv = unit ? dinv2 : dinv1;
    unsigned short* out = unit ? out1 : out0;

    const int l = threadIdx.x & 63;
    const int lg = l >> 4;   // quarter-wave group 0..3
    const int ll = l & 15;   // owns features ll*8..ll*8+7
    const float di = dinv[d];

    float acc[8];
#pragma unroll
    for (int k = 0; k < 8; ++k) acc[k] = 0.0f;

    const int e0 = rowptr[d];
    const int e1 = rowptr[d + 1];
    for (int base = e0; base < e1; base += 64) {
        int cnt = min(64, e1 - base);
        int cs = 0;
        float ws = 0.0f;
        if (base + l < e1) {
            cs = colA[base + l];
            ws = dinv[cs];
        }
        const int ng = (cnt + 3) >> 2;  // wave-uniform group count
        // 3-deep software pipeline over 4-edge groups
        int s0 = __shfl(cs, lg);
        float w0 = __shfl(ws, lg);
        uint4 u0 = *((const uint4*)(h + (size_t)s0 * 128) + ll);
        uint4 u1;
        float w1 = 0.0f;
        if (ng > 1) {
            int s1 = __shfl(cs, 4 + lg);
            w1 = __shfl(ws, 4 + lg);
            u1 = *((const uint4*)(h + (size_t)s1 * 128) + ll);
        }
        for (int g = 2; g < ng; ++g) {
            int s2 = __shfl(cs, g * 4 + lg);
            float w2 = __shfl(ws, g * 4 + lg);
            uint4 u2 = *((const uint4*)(h + (size_t)s2 * 128) + ll);
            acc[0] += w0 * bflo(u0.x);
            acc[1] += w0 * bfhi(u0.x);
            acc[2] += w0 * bflo(u0.y);
            acc[3] += w0 * bfhi(u0.y);
            acc[4] += w0 * bflo(u0.z);
            acc[5] += w0 * bfhi(u0.z);
            acc[6] += w0 * bflo(u0.w);
            acc[7] += w0 * bfhi(u0.w);
            u0 = u1; w0 = w1;
            u1 = u2; w1 = w2;
        }
        if (ng > 1) {
            acc[0] += w0 * bflo(u0.x);
            acc[1] += w0 * bfhi(u0.x);
            acc[2] += w0 * bflo(u0.y);
            acc[3] += w0 * bfhi(u0.y);
            acc[4] += w0 * bflo(u0.z);
            acc[5] += w0 * bfhi(u0.z);
            acc[6] += w0 * bflo(u0.w);
            acc[7] += w0 * bfhi(u0.w);
            u0 = u1; w0 = w1;
        }
        acc[0] += w0 * bflo(u0.x);
        acc[1] += w0 * bfhi(u0.x);
        acc[2] += w0 * bflo(u0.y);
        acc[3] += w0 * bfhi(u0.y);
        acc[4] += w0 * bflo(u0.z);
        acc[5] += w0 * bfhi(u0.z);
        acc[6] += w0 * bflo(u0.w);
        acc[7] += w0 * bfhi(u0.w);
    }
    // combine the 4 groups
#pragma unroll
    for (int k = 0; k < 8; ++k) {
        acc[k] += __shfl_xor(acc[k], 16);
        acc[k] += __shfl_xor(acc[k], 32);
    }
    if (lg == 0) {
        uint4 su = *((const uint4*)(h + (size_t)d * 128) + ll);
        float4 b0 = ((const float4*)bias)[ll * 2];
        float4 b1 = ((const float4*)bias)[ll * 2 + 1];
        float sf[8] = {bflo(su.x), bfhi(su.x), bflo(su.y), bfhi(su.y),
                       bflo(su.z), bfhi(su.z), bflo(su.w), bfhi(su.w)};
        float bb[8] = {b0.x, b0.y, b0.z, b0.w, b1.x, b1.y, b1.z, b1.w};
        unsigned short o[8];
#pragma unroll
        for (int k = 0; k < 8; ++k) {
            float v = di * (acc[k] + di * sf[k]) + bb[k];
            if (do_relu) v = fmaxf(v, 0.0f);
            o[k] = f2bf(v);
        }
        uint4 ov;
        ov.x = (unsigned int)o[0] | ((unsigned int)o[1] << 16);
        ov.y = (unsigned int)o[2] | ((unsigned int)o[3] << 16);
        ov.z = (unsigned int)o[4] | ((unsigned int)o[5] << 16);
        ov.w = (unsigned int)o[6] | ((unsigned int)o[7] << 16);
        *((uint4*)(out + (size_t)d * 128) + ll) = ov;
    }
}

// ---------------- h_diff (f32 out) + h_t (bf16) ----------------
__global__ void k_mix(const unsigned short* __restrict__ F1, const unsigned short* __restrict__ F2,
                      const float* __restrict__ n1, const float* __restrict__ n2,
                      const float* __restrict__ scal, float* __restrict__ hdiff,
                      unsigned short* __restrict__ B1, unsigned short* __restrict__ B2, int total2) {
    const float sa = scal[0];
    const float sm = scal[1];
    int i = blockIdx.x * blockDim.x + threadIdx.x;
    const int stride = gridDim.x * blockDim.x;
    for (; i < total2; i += stride) {
        unsigned int u1 = ((const unsigned int*)F1)[i];
        unsigned int u2 = ((const unsigned int*)F2)[i];
        float a0 = bflo(u1), a1 = bfhi(u1);
        float b0 = bflo(u2), b1 = bfhi(u2);
        float2 x = ((const float2*)n1)[i];
        float2 y = ((const float2*)n2)[i];
        float2 hd;
        hd.x = 0.5f * (a0 + b0);
        hd.y = 0.5f * (a1 + b1);
        ((float2*)hdiff)[i] = hd;
        float h1x = sa * a0 + sm * x.x, h1y = sa * a1 + sm * x.y;
        float h2x = sa * b0 + sm * y.x, h2y = sa * b1 + sm * y.y;
        ((unsigned int*)B1)[i] = (unsigned int)f2bf(h1x) | ((unsigned int)f2bf(h1y) << 16);
        ((unsigned int*)B2)[i] = (unsigned int)f2bf(h2x) | ((unsigned int)f2bf(h2y) << 16);
    }
}

// ---------------- L_diff ----------------
__global__ void k_loss(const unsigned short* __restrict__ P1, const unsigned short* __restrict__ P2,
                       const float* __restrict__ n1, const float* __restrict__ n2,
                       float* __restrict__ outs, int total2, float inv_total) {
    float s = 0.0f;
    int i = blockIdx.x * blockDim.x + threadIdx.x;
    const int stride = gridDim.x * blockDim.x;
    for (; i < total2; i += stride) {
        unsigned int u1 = ((const unsigned int*)P1)[i];
        unsigned int u2 = ((const unsigned int*)P2)[i];
        float2 x = ((const float2*)n1)[i];
        float2 y = ((const float2*)n2)[i];
        float d0 = bflo(u1) - x.x, d1 = bfhi(u1) - x.y;
        float d2 = bflo(u2) - y.x, d3 = bfhi(u2) - y.y;
        s += d0 * d0 + d1 * d1 + d2 * d2 + d3 * d3;
    }
    __shared__ float red[4];
    for (int off = 32; off > 0; off >>= 1) s += __shfl_down(s, off, 64);
    const int lane = threadIdx.x & 63;
    const int wid = threadIdx.x >> 6;
    if (lane == 0) red[wid] = s;
    __syncthreads();
    if (threadIdx.x == 0) {
        float t = red[0] + red[1] + red[2] + red[3];
        atomicAdd(outs, t * inv_total);
    }
}

// ---------------- host ----------------
extern "C" void kernel_launch(void* const* d_in, const int* in_sizes, int n_in,
                              void* d_out, int out_size, void* d_ws, size_t ws_size,
                              hipStream_t stream) {
    const float* X      = (const float*)d_in[0];
    const int*   ei1    = (const int*)d_in[1];
    const int*   ei2    = (const int*)d_in[2];
    const int*   t_p    = (const int*)d_in[3];
    const float* noise1 = (const float*)d_in[4];
    const float* noise2 = (const float*)d_in[5];
    const float* encW1  = (const float*)d_in[6];
    const float* encb1  = (const float*)d_in[7];
    const float* encW2  = (const float*)d_in[8];
    const float* encb2  = (const float*)d_in[9];
    const float* tmW1   = (const float*)d_in[10];
    const float* tmb1   = (const float*)d_in[11];
    const float* tmW2   = (const float*)d_in[12];
    const float* tmb2   = (const float*)d_in[13];
    const float* g1W    = (const float*)d_in[14];
    const float* g1b    = (const float*)d_in[15];
    const float* g2W    = (const float*)d_in[16];
    const float* g2b    = (const float*)d_in[17];
    const float* g3W    = (const float*)d_in[18];
    const float* g3b    = (const float*)d_in[19];

    float* out_hdiff = (float*)d_out;
    float* out_L     = (float*)d_out + (size_t)NN * 128;

    char* p = (char*)d_ws;
    auto alloc = [&](size_t bytes) -> void* {
        void* r = (void*)p;
        p += (bytes + 255) & ~(size_t)255;
        return r;
    };
    int* cnts = (int*)alloc((size_t)4 * NN * sizeof(int));
    int *cnt1 = cnts, *cnt2 = cnts + NN, *fill1 = cnts + 2 * NN, *fill2 = cnts + 3 * NN;
    int* rowptr1 = (int*)alloc((NN + 1) * sizeof(int));
    int* rowptr2 = (int*)alloc((NN + 1) * sizeof(int));
    int* exc     = (int*)alloc((size_t)2 * NN * sizeof(int));
    int* bsum    = (int*)alloc(512 * sizeof(int));
    int* col1    = (int*)alloc((size_t)NE * sizeof(int));
    int* col2    = (int*)alloc((size_t)NE * sizeof(int));
    float* dinv1 = (float*)alloc(NN * sizeof(float));
    float* dinv2 = (float*)alloc(NN * sizeof(float));
    float* scal  = (float*)alloc(256 * sizeof(float));  // [0]=sa [1]=sm [2..129]=cvec
    unsigned short* WtS = (unsigned short*)alloc((size_t)6 * 16384 * sizeof(unsigned short));
    const size_t FB = (size_t)NN * 128;
    unsigned short* Xb = (unsigned short*)alloc(FB * 2);  // also V1d
    unsigned short* A1 = (unsigned short*)alloc(FB * 2);  // enc act v1, then h_t_v1
    unsigned short* A2 = (unsigned short*)alloc(FB * 2);  // enc act v2, then h_t_v2
    unsigned short* D0 = (unsigned short*)alloc(FB * 2);  // GEMM->agg scratch (unit0)
    unsigned short* D1 = (unsigned short*)alloc(FB * 2);  // GEMM->agg scratch (unit1)
    unsigned short* F1 = (unsigned short*)alloc(FB * 2);  // h0_v1, then pred_v1
    unsigned short* F2 = (unsigned short*)alloc(FB * 2);  // h0_v2, then V2d, then pred_v2
    unsigned short* V1d = Xb;
    unsigned short* V2d = F2;

    const unsigned short* W_enc1 = WtS;
    const unsigned short* W_enc2 = WtS + 1 * 16384;
    const unsigned short* W_g1a  = WtS + 2 * 16384;
    const unsigned short* W_g1b  = WtS + 3 * 16384;
    const unsigned short* W_g2   = WtS + 4 * 16384;
    const unsigned short* W_g3   = WtS + 5 * 16384;

    const int* src1 = ei1;
    const int* dst1 = ei1 + NE;
    const int* src2 = ei2;
    const int* dst2 = ei2 + NE;

    const int nbE2   = divup(2 * NE, 256);
    const int nbAgg  = divup(2 * NN, 4);      // 25000 blocks (4 waves/block)
    const int nbScan = divup(2 * NN, SCAN_B); // 391
    const int total2 = NN * 64;

    // --- preprocessing (7 dispatches) ---
    k_prep<<<2048, 256, 0, stream>>>(X, encW1, encW2, g1W, g2W, g3W, cnts, Xb, WtS);
    k_scalars<<<1, 128, 0, stream>>>(t_p, tmW1, tmb1, tmW2, tmb2, g1W, scal, out_L);
    k_hist2<<<nbE2, 256, 0, stream>>>(dst1, dst2, cnt1, cnt2);
    k_scan1<<<nbScan, 256, 0, stream>>>(cnts, exc, bsum, 2 * NN);
    k_scan2<<<1, 512, 0, stream>>>(bsum, nbScan);
    k_scan3<<<nbScan, 256, 0, stream>>>(exc, bsum, cnts, rowptr1, rowptr2, dinv1, dinv2);
    k_fill2<<<nbE2, 256, 0, stream>>>(src1, dst1, src2, dst2, rowptr1, rowptr2,
                                      fill1, fill2, col1, col2);

    // --- encoder layer 1: shared GEMM, dual agg ---
    k_mgemm2<<<NBG, 256, 0, stream>>>(Xb, nullptr, D0, nullptr, nullptr, nullptr,
                                      W_enc1, nullptr, nullptr);
    k_agg2<<<nbAgg, 256, 0, stream>>>(D0, D0, rowptr1, col1, dinv1, rowptr2, col2, dinv2,
                                      encb1, A1, A2, 1);
    // --- encoder layer 2 ---
    k_mgemm2<<<2 * NBG, 256, 0, stream>>>(A1, nullptr, D0, A2, nullptr, D1,
                                          W_enc2, nullptr, nullptr);
    k_agg2<<<nbAgg, 256, 0, stream>>>(D0, D1, rowptr1, col1, dinv1, rowptr2, col2, dinv2,
                                      encb2, F1, F2, 0);  // h0_v1, h0_v2

    // --- h_diff out (f32) + h_t (bf16 into A1/A2) ---
    k_mix<<<2048, 256, 0, stream>>>(F1, F2, noise1, noise2, scal, out_hdiff, A1, A2, total2);

    // --- denoiser layer 1 (dual GEMM + cvec, cross inputs) ---
    k_mgemm2<<<2 * NBG, 256, 0, stream>>>(A1, A2, D0, A2, A1, D1, W_g1a, W_g1b, scal + 2);
    k_agg2<<<nbAgg, 256, 0, stream>>>(D0, D1, rowptr1, col1, dinv1, rowptr2, col2, dinv2,
                                      g1b, V1d, V2d, 1);
    // --- denoiser layer 2 ---
    k_mgemm2<<<2 * NBG, 256, 0, stream>>>(V1d, nullptr, D0, V2d, nullptr, D1,
                                          W_g2, nullptr, nullptr);
    k_agg2<<<nbAgg, 256, 0, stream>>>(D0, D1, rowptr1, col1, dinv1, rowptr2, col2, dinv2,
                                      g2b, V1d, V2d, 1);
    // --- denoiser layer 3 ---
    k_mgemm2<<<2 * NBG, 256, 0, stream>>>(V1d, nullptr, D0, V2d, nullptr, D1,
                                          W_g3, nullptr, nullptr);
    k_agg2<<<nbAgg, 256, 0, stream>>>(D0, D1, rowptr1, col1, dinv1, rowptr2, col2, dinv2,
                                      g3b, F1, F2, 0);  // pred_v1, pred_v2

    // --- loss ---
    k_loss<<<2048, 256, 0, stream>>>(F1, F2, noise1, noise2, out_L, total2,
                                     1.0f / (float)((size_t)NN * 128));
}